// Round 4
// baseline (179.105 us; speedup 1.0000x reference)
//
#include <hip/hip_runtime.h>

#define PP 16
#define DD 64
#define RR 32
#define KK 64
#define NBT 4096   // B*T

#define LOG2E 1.4426950408889634f
#define LN2   0.6931471805599453f
#define D2_CUT 25.0f   // keep pairs with d2 <= d2min + CUT; rel err <= ~e^-25 vs dominant term
#define MAXPAIRS 496

static __device__ __forceinline__ float fast_log2(float x) { return __builtin_amdgcn_logf(x); }
static __device__ __forceinline__ float fast_exp2(float x) { return __builtin_amdgcn_exp2f(x); }
static __device__ __forceinline__ float fast_rcp(float x)  { return __builtin_amdgcn_rcpf(x); }

// One block, 1024 threads: thread t=(r,s). cc[r]=||c_r||^2; d2min over r<s; compact
// pairs with d2 <= d2min+CUT into plist as (omega, int(r*32+s)). meta[0]=np,
// meta[1]=done-counter zeroed here (stream-ordered before sheaf kernel).
__global__ __launch_bounds__(1024) void prune_kernel(const float* __restrict__ c,
                                                     float* __restrict__ cc,
                                                     int* __restrict__ meta,
                                                     float2* __restrict__ plist) {
    __shared__ float red[16];
    __shared__ float dmin_sh;
    __shared__ int cnt;
    const int t = threadIdx.x;
    const int r = t >> 5, s = t & 31;
    const bool active = s > r;
    const float4* c4 = (const float4*)c;

    float d2 = 0.f;
#pragma unroll
    for (int d4 = 0; d4 < 16; ++d4) {
        float4 a = c4[r * 16 + d4];
        float4 b = c4[s * 16 + d4];
        float dx = a.x - b.x, dy = a.y - b.y, dz = a.z - b.z, dw = a.w - b.w;
        d2 = fmaf(dx, dx, d2); d2 = fmaf(dy, dy, d2);
        d2 = fmaf(dz, dz, d2); d2 = fmaf(dw, dw, d2);
    }
    if (t == 0) cnt = 0;
    float dm = active ? d2 : 3.4e38f;
#pragma unroll
    for (int off = 32; off > 0; off >>= 1) dm = fminf(dm, __shfl_down(dm, off, 64));
    if ((t & 63) == 0) red[t >> 6] = dm;
    __syncthreads();
    if (t < 64) {
        float v = (t < 16) ? red[t] : 3.4e38f;
#pragma unroll
        for (int off = 8; off > 0; off >>= 1) v = fminf(v, __shfl_down(v, off, 64));
        if (t == 0) dmin_sh = v;
    }
    __syncthreads();
    if (active && d2 <= dmin_sh + D2_CUT) {
        int idx = atomicAdd(&cnt, 1);
        plist[idx] = make_float2(fast_exp2(-d2 * LOG2E), __int_as_float(t));
    }
    if (t < RR) {
        float a2 = 0.f;
#pragma unroll
        for (int d4 = 0; d4 < 16; ++d4) {
            float4 v = c4[t * 16 + d4];
            a2 = fmaf(v.x, v.x, a2); a2 = fmaf(v.y, v.y, a2);
            a2 = fmaf(v.z, v.z, a2); a2 = fmaf(v.w, v.w, a2);
        }
        cc[t] = a2;
    }
    __syncthreads();
    if (t == 0) { meta[0] = cnt; meta[1] = 0; }
}

__global__ __launch_bounds__(256) void sheaf2_kernel(
    const float* __restrict__ m, const float* __restrict__ w,
    const float* __restrict__ p, const float* __restrict__ c,
    const float* __restrict__ cc, const int* __restrict__ meta,
    const float2* __restrict__ plist, float* __restrict__ partials,
    float* __restrict__ out) {
    // Aliased LDS: smem_mp = m (phase 1) then plist (phase 5); smem_cpl = c^T
    // (phase 1) then (pbar, pbar*log2 pbar) (phases 4-5).
    __shared__ __align__(16) float  smem_mp[PP * DD];     // 4096 B
    __shared__ __align__(16) float  sm_p[PP * KK];        // 4096 B
    __shared__ __align__(16) float2 smem_cpl[RR * KK];    // 16384 B
    __shared__ float sm_mass[PP * 36];                    // 2304 B (pad 36)
    __shared__ float sm_w[PP];
    __shared__ float sred[4];
    __shared__ int   sm_last;

    float*  sm_m     = smem_mp;
    float2* sm_plist = (float2*)smem_mp;   // 496*8 = 3968 <= 4096
    float2* sm_cT2   = smem_cpl;           // 32*33 float2 = 8448 <= 16384
    float2* sm_pl    = smem_cpl;

    const int tid = threadIdx.x;
    const int bt  = blockIdx.x;
    const int k   = tid & 63;
    const int wv  = tid >> 6;
    const int np  = meta[0];   // uniform -> s_load

    // ---- stage everything with minimal, coalesced global loads ----
    {
        const float4* m4 = (const float4*)(m + (size_t)bt * PP * DD);
        const float4* p4 = (const float4*)(p + (size_t)bt * PP * KK);
        ((float4*)sm_m)[tid] = m4[tid];
        ((float4*)sm_p)[tid] = p4[tid];
        const float2* c2 = (const float2*)c;
#pragma unroll
        for (int it = 0; it < 4; ++it) {
            int idx = tid + 256 * it;
            sm_cT2[(idx & 31) * 33 + (idx >> 5)] = c2[idx];
        }
        if (tid < PP) sm_w[tid] = w[(size_t)bt * PP + tid];
    }
    __syncthreads();

    // ---- phase 1: logits[p][r] = 2*m.c - ||c||^2  (||m||^2 cancels in softmax) ----
    {
        const int r  = tid & 31;
        const int pg = tid >> 5;  // rows pg and pg+8
        float ccr = cc[r];
        float acc0 = 0.f, acc1 = 0.f;
#pragma unroll
        for (int d4 = 0; d4 < 16; ++d4) {
            float2 ca = sm_cT2[(2 * d4) * 33 + r];
            float2 cb = sm_cT2[(2 * d4 + 1) * 33 + r];
            float4 ma = *(const float4*)&sm_m[pg * DD + d4 * 4];         // broadcast
            float4 mb = *(const float4*)&sm_m[(pg + 8) * DD + d4 * 4];   // broadcast
            acc0 = fmaf(ma.x, ca.x, acc0); acc0 = fmaf(ma.y, ca.y, acc0);
            acc0 = fmaf(ma.z, cb.x, acc0); acc0 = fmaf(ma.w, cb.y, acc0);
            acc1 = fmaf(mb.x, ca.x, acc1); acc1 = fmaf(mb.y, ca.y, acc1);
            acc1 = fmaf(mb.z, cb.x, acc1); acc1 = fmaf(mb.w, cb.y, acc1);
        }
        sm_mass[pg * 36 + r]       = fmaf(2.f, acc0, -ccr);
        sm_mass[(pg + 8) * 36 + r] = fmaf(2.f, acc1, -ccr);
    }
    __syncthreads();

    // ---- phase 2+3 fused, wave 0 only: softmax over r, *w, col-normalize.
    //      waves 1-3 stage plist into LDS (sm_m is dead now). ----
    if (tid < 64) {
        const int pidx = tid & 15;
        const int rc   = tid >> 4;   // r = rc*8 + j
        float* row = &sm_mass[pidx * 36 + rc * 8];
        float4 va = *(float4*)row;
        float4 vb = *(float4*)(row + 4);
        float v[8] = {va.x, va.y, va.z, va.w, vb.x, vb.y, vb.z, vb.w};
        float mx = v[0];
#pragma unroll
        for (int j = 1; j < 8; ++j) mx = fmaxf(mx, v[j]);
        mx = fmaxf(mx, __shfl_xor(mx, 16, 64));
        mx = fmaxf(mx, __shfl_xor(mx, 32, 64));
        float ssum = 0.f;
#pragma unroll
        for (int j = 0; j < 8; ++j) { v[j] = fast_exp2((v[j] - mx) * LOG2E); ssum += v[j]; }
        ssum += __shfl_xor(ssum, 16, 64);
        ssum += __shfl_xor(ssum, 32, 64);
        float sw = sm_w[pidx] * fast_rcp(ssum);
#pragma unroll
        for (int j = 0; j < 8; ++j) v[j] *= sw;   // start_mass
#pragma unroll
        for (int j = 0; j < 8; ++j) {
            float tj = v[j];
            tj += __shfl_xor(tj, 1, 64);
            tj += __shfl_xor(tj, 2, 64);
            tj += __shfl_xor(tj, 4, 64);
            tj += __shfl_xor(tj, 8, 64);          // total mass for r=(rc,j)
            v[j] *= fast_rcp(tj + 1e-6f);
        }
        *(float4*)row       = make_float4(v[0], v[1], v[2], v[3]);
        *(float4*)(row + 4) = make_float4(v[4], v[5], v[6], v[7]);
    } else {
        for (int i = tid - 64; i < np; i += 192) sm_plist[i] = plist[i];
    }
    __syncthreads();

    // ---- phase 4: pbar[r][k] = sum_p p[p][k]*mass[p][r]; store (pb, pb*log2 pb) ----
    {
        const int r0 = wv * 8;
        float acc[8] = {0.f, 0.f, 0.f, 0.f, 0.f, 0.f, 0.f, 0.f};
#pragma unroll
        for (int pi = 0; pi < PP; ++pi) {
            float pv = sm_p[pi * KK + k];                              // stride-1
            float4 ma = *(const float4*)&sm_mass[pi * 36 + r0];        // broadcast
            float4 mb = *(const float4*)&sm_mass[pi * 36 + r0 + 4];    // broadcast
            acc[0] = fmaf(pv, ma.x, acc[0]);
            acc[1] = fmaf(pv, ma.y, acc[1]);
            acc[2] = fmaf(pv, ma.z, acc[2]);
            acc[3] = fmaf(pv, ma.w, acc[3]);
            acc[4] = fmaf(pv, mb.x, acc[4]);
            acc[5] = fmaf(pv, mb.y, acc[5]);
            acc[6] = fmaf(pv, mb.z, acc[6]);
            acc[7] = fmaf(pv, mb.w, acc[7]);
        }
#pragma unroll
        for (int j = 0; j < 8; ++j) {
            float pb = acc[j];
            float l2 = fast_log2(pb + 1e-8f);
            sm_pl[(r0 + j) * KK + k] = make_float2(pb, pb * l2);
        }
    }
    __syncthreads();

    // ---- phase 5: pruned pairs: omega * [pr*l2pr + ps*l2ps - (pr+ps)*l2(mid)] ----
    {
        float acc = 0.f;
        for (int i = wv; i < np; i += 4) {
            float2 e = sm_plist[i];                 // lane-uniform broadcast
            int rs = __float_as_int(e.y);
            int r = rs >> 5, s = rs & 31;
            float2 a = sm_pl[r * KK + k];
            float2 b = sm_pl[s * KK + k];
            float sum = a.x + b.x;
            float t   = a.y + b.y;
            float lm  = fast_log2(fmaf(0.5f, sum, 1e-8f));
            t = fmaf(-sum, lm, t);
            acc = fmaf(e.x, t, acc);
        }
#pragma unroll
        for (int off = 32; off > 0; off >>= 1) acc += __shfl_down(acc, off, 64);
        if (k == 0) sred[wv] = acc;
    }
    __syncthreads();

    // ---- tail: write partial; last block reduces all partials -> out ----
    int* done = (int*)&(((int*)meta)[1]);
    if (tid == 0) {
        float tot = (sred[0] + sred[1]) + (sred[2] + sred[3]);
        partials[bt] = tot * (0.5f * LN2 / 496.0f);
        __threadfence();
        int old = atomicAdd(done, 1);
        sm_last = (old == NBT - 1) ? 1 : 0;
    }
    __syncthreads();
    if (sm_last) {
        __threadfence();
        const float4* p4 = (const float4*)partials;  // 1024 float4
        float acc = 0.f;
#pragma unroll
        for (int i = 0; i < 4; ++i) {
            float4 v = p4[tid + 256 * i];
            acc += (v.x + v.y) + (v.z + v.w);
        }
#pragma unroll
        for (int off = 32; off > 0; off >>= 1) acc += __shfl_down(acc, off, 64);
        if (k == 0) sred[wv] = acc;
        __syncthreads();
        if (tid == 0) out[0] = (sred[0] + sred[1]) + (sred[2] + sred[3]);
    }
}

extern "C" void kernel_launch(void* const* d_in, const int* in_sizes, int n_in,
                              void* d_out, int out_size, void* d_ws, size_t ws_size,
                              hipStream_t stream) {
    const float* m = (const float*)d_in[0];
    const float* w = (const float*)d_in[1];
    const float* p = (const float*)d_in[2];
    const float* c = (const float*)d_in[3];
    float* out = (float*)d_out;

    float* wsf      = (float*)d_ws;
    int*   meta     = (int*)d_ws;            // [0]=np, [1]=done counter
    float* cc       = wsf + 64;              // 32 floats @ 256 B
    float2* plist   = (float2*)(wsf + 128);  // 496 float2 @ 512 B
    float* partials = wsf + 2048;            // 4096 floats @ 8 KB

    prune_kernel<<<1, 1024, 0, stream>>>(c, cc, meta, plist);
    sheaf2_kernel<<<NBT, 256, 0, stream>>>(m, w, p, c, cc, meta, plist, partials, out);
}

// Round 5
// 114.031 us; speedup vs baseline: 1.5707x; 1.5707x over previous
//
#include <hip/hip_runtime.h>

#define PP 16
#define DD 64
#define RR 32
#define KK 64
#define NBT 4096   // B*T

#define LOG2E 1.4426950408889634f
#define LN2   0.6931471805599453f
#define D2_CUT 25.0f   // keep pairs with d2 <= d2min + CUT; rel err ~e^-25 vs dominant term

static __device__ __forceinline__ float fast_log2(float x) { return __builtin_amdgcn_logf(x); }
static __device__ __forceinline__ float fast_exp2(float x) { return __builtin_amdgcn_exp2f(x); }
static __device__ __forceinline__ float fast_rcp(float x)  { return __builtin_amdgcn_rcpf(x); }

// One block, 1024 threads: thread t=(r,s). cc[r]=||c_r||^2; d2min over r<s; compact
// pairs with d2 <= d2min+CUT into plist as (omega, int(r*32+s)). meta[0]=np.
__global__ __launch_bounds__(1024) void prune_kernel(const float* __restrict__ c,
                                                     float* __restrict__ cc,
                                                     int* __restrict__ meta,
                                                     float2* __restrict__ plist) {
    __shared__ float red[16];
    __shared__ float dmin_sh;
    __shared__ int cnt;
    const int t = threadIdx.x;
    const int r = t >> 5, s = t & 31;
    const bool active = s > r;
    const float4* c4 = (const float4*)c;

    float d2 = 0.f;
#pragma unroll
    for (int d4 = 0; d4 < 16; ++d4) {
        float4 a = c4[r * 16 + d4];
        float4 b = c4[s * 16 + d4];
        float dx = a.x - b.x, dy = a.y - b.y, dz = a.z - b.z, dw = a.w - b.w;
        d2 = fmaf(dx, dx, d2); d2 = fmaf(dy, dy, d2);
        d2 = fmaf(dz, dz, d2); d2 = fmaf(dw, dw, d2);
    }
    if (t == 0) cnt = 0;
    float dm = active ? d2 : 3.4e38f;
#pragma unroll
    for (int off = 32; off > 0; off >>= 1) dm = fminf(dm, __shfl_down(dm, off, 64));
    if ((t & 63) == 0) red[t >> 6] = dm;
    __syncthreads();
    if (t < 64) {
        float v = (t < 16) ? red[t] : 3.4e38f;
#pragma unroll
        for (int off = 8; off > 0; off >>= 1) v = fminf(v, __shfl_down(v, off, 64));
        if (t == 0) dmin_sh = v;
    }
    __syncthreads();
    if (active && d2 <= dmin_sh + D2_CUT) {
        int idx = atomicAdd(&cnt, 1);
        plist[idx] = make_float2(fast_exp2(-d2 * LOG2E), __int_as_float(t));
    }
    if (t < RR) {
        float a2 = 0.f;
#pragma unroll
        for (int d4 = 0; d4 < 16; ++d4) {
            float4 v = c4[t * 16 + d4];
            a2 = fmaf(v.x, v.x, a2); a2 = fmaf(v.y, v.y, a2);
            a2 = fmaf(v.z, v.z, a2); a2 = fmaf(v.w, v.w, a2);
        }
        cc[t] = a2;
    }
    __syncthreads();
    if (t == 0) meta[0] = cnt;
}

__global__ __launch_bounds__(256) void sheaf2_kernel(
    const float* __restrict__ m, const float* __restrict__ w,
    const float* __restrict__ p, const float* __restrict__ c,
    const float* __restrict__ cc, const int* __restrict__ meta,
    const float2* __restrict__ plist, float* __restrict__ partials) {
    // smem_cpl holds c^T (phase 1) then (pbar, pbar*log2 pbar) (phases 4-5).
    __shared__ __align__(16) float  sm_m[PP * DD];        // 4096 B
    __shared__ __align__(16) float  sm_p[PP * KK];        // 4096 B
    __shared__ __align__(16) float2 smem_cpl[RR * KK];    // 16384 B
    __shared__ __align__(16) float  sm_mass[PP * 36];     // 2304 B (pad 36)
    __shared__ float sm_w[PP];
    __shared__ float sred[4];

    float2* sm_cT2 = smem_cpl;   // 32*33 float2 = 8448 B <= 16384
    float2* sm_pl  = smem_cpl;

    const int tid = threadIdx.x;
    const int bt  = blockIdx.x;
    const int k   = tid & 63;
    const int wv  = tid >> 6;
    const int r   = tid & 31;
    const int pg  = tid >> 5;    // 0..7
    const int np  = meta[0];     // uniform -> scalar load

    // ---- stage: one b128 of m, one b128 of p, 4 b64 of c, w ----
    {
        const float4* m4 = (const float4*)(m + (size_t)bt * PP * DD);
        const float4* p4 = (const float4*)(p + (size_t)bt * PP * KK);
        ((float4*)sm_m)[tid] = m4[tid];
        ((float4*)sm_p)[tid] = p4[tid];
        const float2* c2 = (const float2*)c;
#pragma unroll
        for (int it = 0; it < 4; ++it) {
            int idx = tid + 256 * it;
            sm_cT2[(idx & 31) * 33 + (idx >> 5)] = c2[idx];
        }
        if (tid < PP) sm_w[tid] = w[(size_t)bt * PP + tid];
    }
    __syncthreads();

    // ---- phase 1: logits[p][r] = 2*m.c - ||c||^2 (||m||^2 cancels in softmax),
    //      then row-softmax IN REGISTER via half-wave shuffles, scale by w. ----
    {
        float ccr = cc[r];
        float acc0 = 0.f, acc1 = 0.f;
#pragma unroll
        for (int d4 = 0; d4 < 16; ++d4) {
            float2 ca = sm_cT2[(2 * d4) * 33 + r];
            float2 cb = sm_cT2[(2 * d4 + 1) * 33 + r];
            float4 ma = *(const float4*)&sm_m[pg * DD + d4 * 4];         // bcast
            float4 mb = *(const float4*)&sm_m[(pg + 8) * DD + d4 * 4];   // bcast
            acc0 = fmaf(ma.x, ca.x, acc0); acc0 = fmaf(ma.y, ca.y, acc0);
            acc0 = fmaf(ma.z, cb.x, acc0); acc0 = fmaf(ma.w, cb.y, acc0);
            acc1 = fmaf(mb.x, ca.x, acc1); acc1 = fmaf(mb.y, ca.y, acc1);
            acc1 = fmaf(mb.z, cb.x, acc1); acc1 = fmaf(mb.w, cb.y, acc1);
        }
        float l0 = fmaf(2.f, acc0, -ccr);   // row pg, col r (held across half-wave)
        float l1 = fmaf(2.f, acc1, -ccr);   // row pg+8
        float mx0 = l0, mx1 = l1;
#pragma unroll
        for (int off = 1; off <= 16; off <<= 1) {
            mx0 = fmaxf(mx0, __shfl_xor(mx0, off, 64));
            mx1 = fmaxf(mx1, __shfl_xor(mx1, off, 64));
        }
        float e0 = fast_exp2((l0 - mx0) * LOG2E);
        float e1 = fast_exp2((l1 - mx1) * LOG2E);
        float s0 = e0, s1 = e1;
#pragma unroll
        for (int off = 1; off <= 16; off <<= 1) {
            s0 += __shfl_xor(s0, off, 64);
            s1 += __shfl_xor(s1, off, 64);
        }
        float sw0 = sm_w[pg]     * fast_rcp(s0);
        float sw1 = sm_w[pg + 8] * fast_rcp(s1);
        sm_mass[pg * 36 + r]       = e0 * sw0;   // start_mass (pre column-norm)
        sm_mass[(pg + 8) * 36 + r] = e1 * sw1;
    }
    __syncthreads();

    // ---- phase 3 (redundant per wave, no extra barrier): inv_tot[r] in lane r ----
    float inv;
    {
        float tot = 0.f;
#pragma unroll
        for (int pi = 0; pi < PP; ++pi) tot += sm_mass[pi * 36 + r];  // conflict-free
        inv = fast_rcp(tot + 1e-6f);
    }

    // ---- phase 4: pbar[r][k] = inv_r * sum_p p[p][k]*mass[p][r]; store (pb, pb*l2pb) ----
    {
        const int r0 = wv * 8;
        float acc[8] = {0.f, 0.f, 0.f, 0.f, 0.f, 0.f, 0.f, 0.f};
#pragma unroll
        for (int pi = 0; pi < PP; ++pi) {
            float pv = sm_p[pi * KK + k];                              // stride-1
            float4 ma = *(const float4*)&sm_mass[pi * 36 + r0];        // bcast
            float4 mb = *(const float4*)&sm_mass[pi * 36 + r0 + 4];    // bcast
            acc[0] = fmaf(pv, ma.x, acc[0]);
            acc[1] = fmaf(pv, ma.y, acc[1]);
            acc[2] = fmaf(pv, ma.z, acc[2]);
            acc[3] = fmaf(pv, ma.w, acc[3]);
            acc[4] = fmaf(pv, mb.x, acc[4]);
            acc[5] = fmaf(pv, mb.y, acc[5]);
            acc[6] = fmaf(pv, mb.z, acc[6]);
            acc[7] = fmaf(pv, mb.w, acc[7]);
        }
#pragma unroll
        for (int j = 0; j < 8; ++j) {
            float pb = acc[j] * __shfl(inv, r0 + j, 64);   // bcast shuffle
            float l2 = fast_log2(pb + 1e-8f);
            sm_pl[(r0 + j) * KK + k] = make_float2(pb, pb * l2);
        }
    }
    __syncthreads();

    // ---- phase 5: pruned pairs: omega * [pr*l2pr + ps*l2ps - (pr+ps)*l2(mid)] ----
    {
        float acc = 0.f;
        for (int i = wv; i < np; i += 4) {
            float2 e = plist[i];                 // wave-uniform -> scalar, L2-hot
            int rs = __float_as_int(e.y);
            int rr = rs >> 5, ss = rs & 31;
            float2 a = sm_pl[rr * KK + k];
            float2 b = sm_pl[ss * KK + k];
            float sum = a.x + b.x;
            float t   = a.y + b.y;
            float lm  = fast_log2(fmaf(0.5f, sum, 1e-8f));
            t = fmaf(-sum, lm, t);
            acc = fmaf(e.x, t, acc);
        }
#pragma unroll
        for (int off = 32; off > 0; off >>= 1) acc += __shfl_down(acc, off, 64);
        if (k == 0) sred[wv] = acc;
    }
    __syncthreads();
    if (tid == 0) {
        float tot = (sred[0] + sred[1]) + (sred[2] + sred[3]);
        partials[bt] = tot * (0.5f * LN2 / 496.0f);
    }
}

__global__ __launch_bounds__(256) void reduce_kernel(const float* __restrict__ partials,
                                                     float* __restrict__ out) {
    __shared__ float sred[4];
    const int tid = threadIdx.x;
    const float4* p4 = (const float4*)partials;  // 1024 float4
    float acc = 0.f;
#pragma unroll
    for (int i = 0; i < 4; ++i) {
        float4 v = p4[tid + 256 * i];
        acc += (v.x + v.y) + (v.z + v.w);
    }
#pragma unroll
    for (int off = 32; off > 0; off >>= 1) acc += __shfl_down(acc, off, 64);
    if ((tid & 63) == 0) sred[tid >> 6] = acc;
    __syncthreads();
    if (tid == 0) out[0] = (sred[0] + sred[1]) + (sred[2] + sred[3]);
}

extern "C" void kernel_launch(void* const* d_in, const int* in_sizes, int n_in,
                              void* d_out, int out_size, void* d_ws, size_t ws_size,
                              hipStream_t stream) {
    const float* m = (const float*)d_in[0];
    const float* w = (const float*)d_in[1];
    const float* p = (const float*)d_in[2];
    const float* c = (const float*)d_in[3];
    float* out = (float*)d_out;

    float* wsf      = (float*)d_ws;
    int*   meta     = (int*)d_ws;            // [0]=np
    float* cc       = wsf + 64;              // 32 floats @ 256 B
    float2* plist   = (float2*)(wsf + 128);  // up to 496 float2 @ 512 B
    float* partials = wsf + 2048;            // 4096 floats @ 8 KB

    prune_kernel<<<1, 1024, 0, stream>>>(c, cc, meta, plist);
    sheaf2_kernel<<<NBT, 256, 0, stream>>>(m, w, p, c, cc, meta, plist, partials);
    reduce_kernel<<<1, 256, 0, stream>>>(partials, out);
}